// Round 1
// baseline (106.664 us; speedup 1.0000x reference)
//
#include <hip/hip_runtime.h>
#include <stdint.h>

#define BATCH 2048
#define INF 1024
#define OUTF 1024
#define GRID_G 8
#define KTOT 9216   // INF + INF*GRID_G

#define BM 128
#define BN 128
#define BK 32
#define SK 4
#define KC (KTOT / SK)   // 2304
#define MT (BATCH / BM)  // 16
#define NT (OUTF / BN)   // 8

typedef __attribute__((ext_vector_type(8))) short short8_t;
typedef __attribute__((ext_vector_type(4))) float f32x4_t;
typedef __attribute__((ext_vector_type(8))) unsigned short u16x8_t;

__device__ __forceinline__ unsigned short f2bf(float f) {
  unsigned int u = __float_as_uint(f);
  u += 0x7FFFu + ((u >> 16) & 1u);
  return (unsigned short)(u >> 16);
}

__device__ __forceinline__ void async16(void* lds, const void* g) {
  __builtin_amdgcn_global_load_lds(
      (const __attribute__((address_space(1))) void*)g,
      (__attribute__((address_space(3))) void*)lds, 16, 0, 0);
}

// Build W_cat[o][k]: k<1024 -> bf16(base_weight[o][k]); else bf16(coeff[o][k-1024])
// (spline_coeff (O,I,G) row-major == [o][8i+g] already)
__global__ __launch_bounds__(256) void build_w_kernel(
    const float* __restrict__ bw, const float* __restrict__ coeff,
    unsigned short* __restrict__ wc) {
  int id = blockIdx.x * 256 + threadIdx.x;  // one thread per 8 elements
  int row = id / (KTOT / 8);
  int k8 = id - row * (KTOT / 8);
  int k = k8 * 8;
  const float* src = (k < INF) ? (bw + (size_t)row * INF + k)
                               : (coeff + (size_t)row * (INF * GRID_G) + (k - INF));
  const float4* s4 = (const float4*)src;
  float4 a = s4[0], b = s4[1];
  u16x8_t v;
  v[0] = f2bf(a.x); v[1] = f2bf(a.y); v[2] = f2bf(a.z); v[3] = f2bf(a.w);
  v[4] = f2bf(b.x); v[5] = f2bf(b.y); v[6] = f2bf(b.z); v[7] = f2bf(b.w);
  *(u16x8_t*)(wc + (size_t)id * 8) = v;
}

// Build A_cat[b][k]: k<1024 -> bf16(x[b][k]); spline block: one-hot(idx)*bf16(0.1*w)
__global__ __launch_bounds__(256) void build_a_kernel(
    const float* __restrict__ x, const float* __restrict__ grid,
    unsigned short* __restrict__ ac) {
  __shared__ float sg[GRID_G + 1];
  if (threadIdx.x <= GRID_G) sg[threadIdx.x] = grid[threadIdx.x];
  __syncthreads();
  int id = blockIdx.x * 256 + threadIdx.x;  // one per (b,i)
  int b = id >> 10;
  int i = id & 1023;
  float xv = x[id];
  ac[(size_t)b * KTOT + i] = f2bf(xv);
  float xc = fminf(fmaxf(xv, -1.0f), 1.0f);
  int cnt = 0;
#pragma unroll
  for (int j = 0; j <= GRID_G; ++j) cnt += (xc >= sg[j]) ? 1 : 0;
  int idx = cnt - 1;
  idx = idx < 0 ? 0 : (idx > GRID_G - 1 ? GRID_G - 1 : idx);
  float left = sg[idx], right = sg[idx + 1];
  float denom = right - left;
  denom = (denom == 0.0f) ? 1.0f : denom;
  float w = (xc - left) / denom;
  unsigned short val = f2bf(0.1f * w);
  u16x8_t v;
#pragma unroll
  for (int g = 0; g < GRID_G; ++g) v[g] = (g == idx) ? val : (unsigned short)0;
  *(u16x8_t*)(ac + (size_t)b * KTOT + INF + (size_t)i * 8) = v;
}

// Split-K bf16 GEMM: C[b][o] += A_cat[b][k] * W_cat[o][k], m97-style structure.
__global__ __launch_bounds__(256) void gemm_kernel(
    const unsigned short* __restrict__ A, const unsigned short* __restrict__ W,
    float* __restrict__ out) {
  __shared__ unsigned short As[BM * BK];  // 8 KB, linear [128][32]
  __shared__ unsigned short Bs[BN * BK];  // 8 KB

  int bid = blockIdx.x;
  int sk = bid / (MT * NT);
  int t = bid % (MT * NT);
  int mt = t / NT;
  int nt = t % NT;

  int tid = threadIdx.x;
  int wave = tid >> 6;
  int lane = tid & 63;
  int wm = wave >> 1, wn = wave & 1;  // 2x2 wave grid, 64x64 per wave
  int lr = lane & 15, lk = lane >> 4;

  // staging addressing: wave-chunk j covers 16 rows x 32 cols (1KB);
  // lane l -> row +(l>>2), col (l&3)*8 ; matches linear LDS dest + lane*16B
  int srow = lane >> 2;
  int scol = (lane & 3) * 8;
  const unsigned short* ga0 = A + (size_t)(mt * BM + wave * 32 + 0 + srow) * KTOT + sk * KC + scol;
  const unsigned short* ga1 = A + (size_t)(mt * BM + wave * 32 + 16 + srow) * KTOT + sk * KC + scol;
  const unsigned short* gb0 = W + (size_t)(nt * BN + wave * 32 + 0 + srow) * KTOT + sk * KC + scol;
  const unsigned short* gb1 = W + (size_t)(nt * BN + wave * 32 + 16 + srow) * KTOT + sk * KC + scol;
  unsigned short* la0 = &As[(wave * 2 + 0) * 512];
  unsigned short* la1 = &As[(wave * 2 + 1) * 512];
  unsigned short* lb0 = &Bs[(wave * 2 + 0) * 512];
  unsigned short* lb1 = &Bs[(wave * 2 + 1) * 512];

  f32x4_t acc[4][4];
#pragma unroll
  for (int i2 = 0; i2 < 4; ++i2)
#pragma unroll
    for (int j2 = 0; j2 < 4; ++j2) acc[i2][j2] = f32x4_t{0.0f, 0.0f, 0.0f, 0.0f};

  for (int kt = 0; kt < KC / BK; ++kt) {
    async16(la0, ga0);
    async16(la1, ga1);
    async16(lb0, gb0);
    async16(lb1, gb1);
    ga0 += BK; ga1 += BK; gb0 += BK; gb1 += BK;
    __syncthreads();  // drains vmcnt -> LDS tiles ready

    short8_t af[4], bf[4];
#pragma unroll
    for (int mi = 0; mi < 4; ++mi)
      af[mi] = *(const short8_t*)&As[(wm * 64 + mi * 16 + lr) * BK + lk * 8];
#pragma unroll
    for (int ni = 0; ni < 4; ++ni)
      bf[ni] = *(const short8_t*)&Bs[(wn * 64 + ni * 16 + lr) * BK + lk * 8];
#pragma unroll
    for (int mi = 0; mi < 4; ++mi)
#pragma unroll
      for (int ni = 0; ni < 4; ++ni)
        acc[mi][ni] = __builtin_amdgcn_mfma_f32_16x16x32_bf16(af[mi], bf[ni], acc[mi][ni], 0, 0, 0);
    __syncthreads();  // before overwriting LDS next iter
  }

  // epilogue: C/D layout col=lane&15 (n), row=(lane>>4)*4+reg (m)
#pragma unroll
  for (int mi = 0; mi < 4; ++mi) {
#pragma unroll
    for (int ni = 0; ni < 4; ++ni) {
      int col = nt * BN + wn * 64 + ni * 16 + lr;
#pragma unroll
      for (int r = 0; r < 4; ++r) {
        int rowm = mt * BM + wm * 64 + mi * 16 + lk * 4 + r;
        atomicAdd(&out[(size_t)rowm * OUTF + col], acc[mi][ni][r]);
      }
    }
  }
}

extern "C" void kernel_launch(void* const* d_in, const int* in_sizes, int n_in,
                              void* d_out, int out_size, void* d_ws, size_t ws_size,
                              hipStream_t stream) {
  const float* x = (const float*)d_in[0];
  const float* bw = (const float*)d_in[1];
  const float* coeff = (const float*)d_in[2];
  const float* grid = (const float*)d_in[3];
  float* out = (float*)d_out;

  unsigned short* Acat = (unsigned short*)d_ws;              // 2048*9216*2 = 37.75 MB
  unsigned short* Wcat = Acat + (size_t)BATCH * KTOT;        // 1024*9216*2 = 18.87 MB

  hipMemsetAsync(d_out, 0, (size_t)out_size * sizeof(float), stream);
  build_w_kernel<<<OUTF * (KTOT / 8) / 256, 256, 0, stream>>>(bw, coeff, Wcat);
  build_a_kernel<<<BATCH * INF / 256, 256, 0, stream>>>(x, grid, Acat);
  gemm_kernel<<<SK * MT * NT, 256, 0, stream>>>(Acat, Wcat, out);
}